// Round 6
// baseline (185.680 us; speedup 1.0000x reference)
//
#include <hip/hip_runtime.h>
#include <hip/hip_fp16.h>

// Problem constants
#define NV   20000
#define KK   3
#define INF  150
#define HH   64
#define OO   128
#define PT   80
#define KTOT 5120      // 80 bins * 64 h
#define NB   80        // vertices per geo block (v17: 250 blocks x ALL 80 bins,
                       //  no split-K -> norm kernel fused into geo epilogue)
#define RS   72        // pch v-row stride, halves (64 + 8 pad)
#define CB   (NB * RS) // 5760 halves = 11520 B per buffer
#define XS   168       // x/W1 LDS col stride, halves (prep kernel)
#define CPS  81        // conn entries stride per vertex (80 + 1 pad)

typedef _Float16 fh8 __attribute__((ext_vector_type(8)));   // MFMA A/B frag (4 VGPRs)
typedef __attribute__((ext_vector_type(4))) float f32x4;    // MFMA C/D frag
typedef __attribute__((ext_vector_type(8))) unsigned short u16x8;

__device__ __forceinline__ unsigned short f2h(float f) {
    return __half_as_ushort(__float2half(f));
}
__device__ __forceinline__ _Float16 u2h(unsigned short u) {
    union { unsigned short s; _Float16 h; } c; c.s = u; return c.h;
}

// ---------------------------------------------------------------------------
// Fused prep kernel (v16, unchanged).
// Blocks 0..127: transpose Wg[o] -> W2 [S][o][kk] fp16 via LDS.
// Blocks 128..752: h = relu(x @ W1^T) -> fp16, 32 rows/block via MFMA.
// ---------------------------------------------------------------------------
__global__ __launch_bounds__(256) void prep_kernel(
    const float* __restrict__ Wg, const float* __restrict__ x,
    const float* __restrict__ W1, unsigned short* __restrict__ W2,
    unsigned short* __restrict__ hb) {
    __shared__ __align__(16) unsigned char smem[32256];
    const int tid = threadIdx.x;

    if (blockIdx.x < 128) {
        float* lds = (float*)smem;                 // 64*81 words
        const int o = blockIdx.x;
        const float* src = Wg + o * KTOT;
        for (int e = tid; e < KTOT / 4; e += 256) {
            const float4 v4 = ((const float4*)src)[e];
            const int t = e * 4;
            const int h = t / 80, bin = t - h * 80;
            lds[h * 81 + bin]     = v4.x;
            lds[h * 81 + bin + 1] = v4.y;
            lds[h * 81 + bin + 2] = v4.z;
            lds[h * 81 + bin + 3] = v4.w;
        }
        __syncthreads();
        for (int e = tid; e < KTOT / 2; e += 256) {
            const int t = e * 2;
            const unsigned int h0 = f2h(lds[(t & 63) * 81 + (t >> 6)]);
            const unsigned int h1 = f2h(lds[((t + 1) & 63) * 81 + ((t + 1) >> 6)]);
            *(unsigned int*)(W2 + (t >> 5) * 4096 + o * 32 + (t & 31)) =
                h0 | (h1 << 16);
        }
        return;
    }

    unsigned short* xs = (unsigned short*)smem;    // 32*168
    unsigned short* ws = xs + 32 * XS;             // 64*168
    const int n0 = (blockIdx.x - 128) * 32;

    {
        const float2* x2 = (const float2*)(x + (size_t)n0 * INF);
        for (int e = tid; e < 32 * (INF / 2); e += 256) {
            const int f = e * 2;
            const int r = f / INF, c = f - r * INF;
            const float2 v = x2[e];
            const unsigned int p =
                (unsigned int)f2h(v.x) | ((unsigned int)f2h(v.y) << 16);
            *(unsigned int*)(xs + r * XS + c) = p;
        }
    }
    for (int e = tid; e < 32 * 9; e += 256) {
        const int r = e / 9, c2 = e - r * 9;
        *(unsigned int*)(xs + r * XS + 150 + c2 * 2) = 0;
    }
    {
        const float2* w2p = (const float2*)W1;
        for (int e = tid; e < 64 * (INF / 2); e += 256) {
            const int f = e * 2;
            const int r = f / INF, c = f - r * INF;
            const float2 v = w2p[e];
            const unsigned int p =
                (unsigned int)f2h(v.x) | ((unsigned int)f2h(v.y) << 16);
            *(unsigned int*)(ws + r * XS + c) = p;
        }
    }
    for (int e = tid; e < 64 * 9; e += 256) {
        const int r = e / 9, c2 = e - r * 9;
        *(unsigned int*)(ws + r * XS + 150 + c2 * 2) = 0;
    }
    __syncthreads();

    const int wv   = tid >> 6;
    const int lane = tid & 63;
    const int q    = lane >> 4;
    const int r16  = lane & 15;
    const int o0   = wv * 16;

    f32x4 acc0 = {0.f, 0.f, 0.f, 0.f};
    f32x4 acc1 = acc0;
    #pragma unroll
    for (int s = 0; s < 5; s++) {
        const int kb = s * 32 + q * 8;
        fh8 a0 = *(const fh8*)(xs + r16 * XS + kb);
        fh8 a1 = *(const fh8*)(xs + (16 + r16) * XS + kb);
        fh8 b  = *(const fh8*)(ws + (o0 + r16) * XS + kb);
        acc0 = __builtin_amdgcn_mfma_f32_16x16x32_f16(a0, b, acc0, 0, 0, 0);
        acc1 = __builtin_amdgcn_mfma_f32_16x16x32_f16(a1, b, acc1, 0, 0, 0);
    }
    #pragma unroll
    for (int r = 0; r < 4; r++) {
        float v0 = acc0[r] > 0.f ? acc0[r] : 0.f;
        float v1 = acc1[r] > 0.f ? acc1[r] : 0.f;
        hb[(n0 + q * 4 + r) * HH + o0 + r16]      = f2h(v0);
        hb[(n0 + 16 + q * 4 + r) * HH + o0 + r16] = f2h(v1);
    }
}

// ---------------------------------------------------------------------------
// Geo kernel v17: full-depth blocks + fused bias/L2-norm epilogue.
// R5 post-mortem: prep/norm vectorization moved nothing (159->162); the
// ~97us non-geo residual is launch/reset overhead + small kernels. Only
// structural lever left: DELETE the norm kernel. Each block now owns all
// 80 bins of its NB=80 rows (250 blocks x 512 thr, 20000=250*80 exact,
// single round, ~1 block/CU), so output rows complete in-block and
// bias + rsqrt(sum v^2) fuse into the epilogue. Deletes: norm launch,
// parts workspace (30 MB HBM), fp16 partial rounding. Per-wave W2 /
// gather / store patterns kept IDENTICAL to v14 (8 o-waves, 1 o-frag
// each) -- v15 showed perturbing those costs +28 MB HBM via L2 thrash.
// Conn for all 80 bins fits LDS (103.7 KB, CPS=81 pad for bank spread);
// chunk machinery deleted. Epilogue: 2 shfl_xor steps -> 4-lane partials
// -> LDS reduce in the dead pch buffer -> broadcast rsqrt -> fp32 store.
// Risk accepted: 1 block/CU loses cross-block barrier overlap (falsifier:
// geo > 75us).
// ---------------------------------------------------------------------------
__global__ __launch_bounds__(512, 2) void geo_kernel(
    const int*   __restrict__ conn_idx, const float* __restrict__ conn_w,
    const unsigned short* __restrict__ W2, const unsigned short* __restrict__ hb,
    const float* __restrict__ bg, float* __restrict__ out) {
    __shared__ __align__(16) unsigned short pch[2 * CB];        // 23040 B
    __shared__ __align__(16) unsigned short cp[NB * CPS * 8];   // 103680 B

    const int tid  = threadIdx.x;
    const int n0   = blockIdx.x * NB;
    const int wv   = tid >> 6;                   // wave 0..7 = o-frag
    const int lane = tid & 63;
    const int q    = lane >> 4;
    const int r16  = lane & 15;
    const int j8   = tid & 7;                    // 16B segment of h row
    const int v0   = tid >> 3;                   // vertex 0..63 (lo also +64)
    const bool lo  = (v0 < 16);                  // rows 64..79

    // All 80 bins of conn -> LDS, packed cp[v][cc] = [i0,i1,i2,w0,w1,w2,0,0]
    for (int e = tid; e < NB * 80; e += 512) {
        const int v = e / 80, cc = e - v * 80;
        const int g = (n0 + v) * (PT * KK) + cc * KK;
        u16x8 pk;
        pk[0] = (unsigned short)conn_idx[g];
        pk[1] = (unsigned short)conn_idx[g + 1];
        pk[2] = (unsigned short)conn_idx[g + 2];
        pk[3] = f2h(conn_w[g]);
        pk[4] = f2h(conn_w[g + 1]);
        pk[5] = f2h(conn_w[g + 2]);
        pk[6] = 0; pk[7] = 0;
        *(u16x8*)(cp + (v * CPS + cc) * 8) = pk;
    }

    f32x4 acc[5];
    #pragma unroll
    for (int m = 0; m < 5; m++) acc[m] = (f32x4){0.f, 0.f, 0.f, 0.f};

    u16x8 pa, pc;        // packed conn for rows v0 and (lo) v0+64
    fh8   hva0, hva1, hva2, hvc0, hvc1, hvc2;

    auto loadg = [&](int cc) {                   // conn b128 + 3..6 gathers
        pa = *(const u16x8*)(cp + (v0 * CPS + cc) * 8);
        hva0 = *(const fh8*)(hb + (int)pa[0] * HH + j8 * 8);
        hva1 = *(const fh8*)(hb + (int)pa[1] * HH + j8 * 8);
        hva2 = *(const fh8*)(hb + (int)pa[2] * HH + j8 * 8);
        if (lo) {                                // wave-uniform (waves 0..1)
            pc = *(const u16x8*)(cp + ((v0 + 64) * CPS + cc) * 8);
            hvc0 = *(const fh8*)(hb + (int)pc[0] * HH + j8 * 8);
            hvc1 = *(const fh8*)(hb + (int)pc[1] * HH + j8 * 8);
            hvc2 = *(const fh8*)(hb + (int)pc[2] * HH + j8 * 8);
        }
    };
    auto cwr = [&](unsigned short* buf) {        // combine + 1..2 LDS b128 writes
        const _Float16 a0 = u2h(pa[3]), a1 = u2h(pa[4]), a2 = u2h(pa[5]);
        const fh8 A0 = {a0, a0, a0, a0, a0, a0, a0, a0};
        const fh8 A1 = {a1, a1, a1, a1, a1, a1, a1, a1};
        const fh8 A2 = {a2, a2, a2, a2, a2, a2, a2, a2};
        fh8 ra = hva0 * A0 + hva1 * A1 + hva2 * A2;
        *(fh8*)(buf + v0 * RS + j8 * 8) = ra;
        if (lo) {
            const _Float16 c0 = u2h(pc[3]), c1 = u2h(pc[4]), c2 = u2h(pc[5]);
            const fh8 C0 = {c0, c0, c0, c0, c0, c0, c0, c0};
            const fh8 C1 = {c1, c1, c1, c1, c1, c1, c1, c1};
            const fh8 C2 = {c2, c2, c2, c2, c2, c2, c2, c2};
            fh8 rc = hvc0 * C0 + hvc1 * C1 + hvc2 * C2;
            *(fh8*)(buf + (v0 + 64) * RS + j8 * 8) = rc;
        }
    };
    auto mfmaph = [&](const unsigned short* buf, int cc) {   // 10 MFMA/wave
        const unsigned short* wp =
            W2 + (cc * 2) * 4096 + (wv * 16 + r16) * 32 + q * 8;
        const fh8 bf0 = *(const fh8*)(wp);
        const fh8 bf1 = *(const fh8*)(wp + 4096);
        #pragma unroll
        for (int s = 0; s < 2; s++) {
            const int ao = s * 32 + q * 8;
            const fh8 bf = s ? bf1 : bf0;
            #pragma unroll
            for (int m = 0; m < 5; m++) {
                fh8 af = *(const fh8*)(buf + (m * 16 + r16) * RS + ao);
                acc[m] = __builtin_amdgcn_mfma_f32_16x16x32_f16(af, bf, acc[m], 0, 0, 0);
            }
        }
    };

    __syncthreads();                             // cp visible

    // Prologue: bin 0 staged into buffer 0
    loadg(0);
    cwr(pch);
    __syncthreads();

    #pragma unroll 1
    for (int cc = 0; cc < 80; cc++) {
        if (cc + 1 < 80) loadg(cc + 1);          // gathers in flight over MFMA
        mfmaph(&pch[(cc & 1) * CB], cc);
        if (cc + 1 < 80) cwr(&pch[((cc + 1) & 1) * CB]);
        __syncthreads();
    }

    // -------- fused epilogue: v = acc + bg; out = v * rsqrt(sum v^2) -------
    // pch is dead after the final barrier -> reuse as reduction scratch.
    float* sums = (float*)pch;                   // [80][33] partial sumsq
    float* rsy  = sums + NB * 33;                // [80] rsqrt per row

    const float bias = bg[wv * 16 + r16];
    float ps[5][4];
    #pragma unroll
    for (int m = 0; m < 5; m++) {
        f32x4 v = acc[m];
        v[0] += bias; v[1] += bias; v[2] += bias; v[3] += bias;
        acc[m] = v;
        #pragma unroll
        for (int r = 0; r < 4; r++) {
            float s2 = v[r] * v[r];
            s2 += __shfl_xor(s2, 1, 16);         // reduce over r16 within
            s2 += __shfl_xor(s2, 2, 16);         //   4-lane groups
            ps[m][r] = s2;
        }
    }
    if ((r16 & 3) == 0) {                        // 4 writers per q-group
        #pragma unroll
        for (int m = 0; m < 5; m++)
            #pragma unroll
            for (int r = 0; r < 4; r++)
                sums[(m * 16 + q * 4 + r) * 33 + wv * 4 + (r16 >> 2)] = ps[m][r];
    }
    __syncthreads();
    if (tid < NB) {                              // final 32-way reduce per row
        float tot = 0.f;
        #pragma unroll
        for (int c = 0; c < 32; c++) tot += sums[tid * 33 + c];
        rsy[tid] = rsqrtf(tot);
    }
    __syncthreads();
    #pragma unroll
    for (int m = 0; m < 5; m++) {
        const int rb = n0 + m * 16 + q * 4;
        #pragma unroll
        for (int r = 0; r < 4; r++) {
            const float rs = rsy[m * 16 + q * 4 + r];   // LDS broadcast
            out[(rb + r) * OO + wv * 16 + r16] = acc[m][r] * rs;
        }
    }
}

// ---------------------------------------------------------------------------
extern "C" void kernel_launch(void* const* d_in, const int* in_sizes, int n_in,
                              void* d_out, int out_size, void* d_ws, size_t ws_size,
                              hipStream_t stream) {
    const float* x        = (const float*)d_in[0];
    const int*   conn_idx = (const int*)  d_in[1];
    const float* conn_w   = (const float*)d_in[2];
    const float* W1       = (const float*)d_in[3];
    const float* Wg       = (const float*)d_in[4];
    const float* bg       = (const float*)d_in[5];
    float*       out      = (float*)d_out;

    unsigned short* W2    = (unsigned short*)d_ws;         // 655,360 fp16 (1.31 MB)
    unsigned short* hb    = W2 + OO * KTOT;                // 1,280,000 fp16 (2.56 MB)

    hipLaunchKernelGGL(prep_kernel, dim3(128 + NV / 32), dim3(256), 0, stream,
                       Wg, x, W1, W2, hb);
    hipLaunchKernelGGL(geo_kernel, dim3(NV / NB), dim3(512), 0, stream,
                       conn_idx, conn_w, W2, hb, bg, out);
}

// Round 7
// 158.242 us; speedup vs baseline: 1.1734x; 1.1734x over previous
//
#include <hip/hip_runtime.h>
#include <hip/hip_fp16.h>

// Problem constants
#define NV   20000
#define KK   3
#define INF  150
#define HH   64
#define OO   128
#define PT   80
#define KTOT 5120      // 80 bins * 64 h
#define NB   80        // vertices per geo block (v18: 250 tiles x 2 ks = 500 blocks)
#define RS   72        // pch v-row stride, halves (64 + 8 pad)
#define CB   (NB * RS) // 5760 halves = 11520 B per buffer
#define XS   168       // x/W1 LDS col stride, halves (prep kernel)
#define NBIN 40        // bins per K-slice
#define CPS  41        // conn bin-dim stride (40 + 1 pad -> v0 reads spread banks)

typedef _Float16 fh8 __attribute__((ext_vector_type(8)));   // MFMA A/B frag (4 VGPRs)
typedef __attribute__((ext_vector_type(4))) float f32x4;    // MFMA C/D frag
typedef __attribute__((ext_vector_type(8))) unsigned short u16x8;

__device__ __forceinline__ unsigned short f2h(float f) {
    return __half_as_ushort(__float2half(f));
}
__device__ __forceinline__ float h2f(unsigned short u) {
    return __half2float(__ushort_as_half(u));
}
__device__ __forceinline__ _Float16 u2h(unsigned short u) {
    union { unsigned short s; _Float16 h; } c; c.s = u; return c.h;
}

// ---------------------------------------------------------------------------
// Fused prep kernel (v16, unchanged).
// Blocks 0..127: transpose Wg[o] -> W2 [S][o][kk] fp16 via LDS.
// Blocks 128..752: h = relu(x @ W1^T) -> fp16, 32 rows/block via MFMA.
// ---------------------------------------------------------------------------
__global__ __launch_bounds__(256) void prep_kernel(
    const float* __restrict__ Wg, const float* __restrict__ x,
    const float* __restrict__ W1, unsigned short* __restrict__ W2,
    unsigned short* __restrict__ hb) {
    __shared__ __align__(16) unsigned char smem[32256];
    const int tid = threadIdx.x;

    if (blockIdx.x < 128) {
        float* lds = (float*)smem;                 // 64*81 words
        const int o = blockIdx.x;
        const float* src = Wg + o * KTOT;
        for (int e = tid; e < KTOT / 4; e += 256) {
            const float4 v4 = ((const float4*)src)[e];
            const int t = e * 4;
            const int h = t / 80, bin = t - h * 80;
            lds[h * 81 + bin]     = v4.x;
            lds[h * 81 + bin + 1] = v4.y;
            lds[h * 81 + bin + 2] = v4.z;
            lds[h * 81 + bin + 3] = v4.w;
        }
        __syncthreads();
        for (int e = tid; e < KTOT / 2; e += 256) {
            const int t = e * 2;
            const unsigned int h0 = f2h(lds[(t & 63) * 81 + (t >> 6)]);
            const unsigned int h1 = f2h(lds[((t + 1) & 63) * 81 + ((t + 1) >> 6)]);
            *(unsigned int*)(W2 + (t >> 5) * 4096 + o * 32 + (t & 31)) =
                h0 | (h1 << 16);
        }
        return;
    }

    unsigned short* xs = (unsigned short*)smem;    // 32*168
    unsigned short* ws = xs + 32 * XS;             // 64*168
    const int n0 = (blockIdx.x - 128) * 32;

    {
        const float2* x2 = (const float2*)(x + (size_t)n0 * INF);
        for (int e = tid; e < 32 * (INF / 2); e += 256) {
            const int f = e * 2;
            const int r = f / INF, c = f - r * INF;
            const float2 v = x2[e];
            const unsigned int p =
                (unsigned int)f2h(v.x) | ((unsigned int)f2h(v.y) << 16);
            *(unsigned int*)(xs + r * XS + c) = p;
        }
    }
    for (int e = tid; e < 32 * 9; e += 256) {
        const int r = e / 9, c2 = e - r * 9;
        *(unsigned int*)(xs + r * XS + 150 + c2 * 2) = 0;
    }
    {
        const float2* w2p = (const float2*)W1;
        for (int e = tid; e < 64 * (INF / 2); e += 256) {
            const int f = e * 2;
            const int r = f / INF, c = f - r * INF;
            const float2 v = w2p[e];
            const unsigned int p =
                (unsigned int)f2h(v.x) | ((unsigned int)f2h(v.y) << 16);
            *(unsigned int*)(ws + r * XS + c) = p;
        }
    }
    for (int e = tid; e < 64 * 9; e += 256) {
        const int r = e / 9, c2 = e - r * 9;
        *(unsigned int*)(ws + r * XS + 150 + c2 * 2) = 0;
    }
    __syncthreads();

    const int wv   = tid >> 6;
    const int lane = tid & 63;
    const int q    = lane >> 4;
    const int r16  = lane & 15;
    const int o0   = wv * 16;

    f32x4 acc0 = {0.f, 0.f, 0.f, 0.f};
    f32x4 acc1 = acc0;
    #pragma unroll
    for (int s = 0; s < 5; s++) {
        const int kb = s * 32 + q * 8;
        fh8 a0 = *(const fh8*)(xs + r16 * XS + kb);
        fh8 a1 = *(const fh8*)(xs + (16 + r16) * XS + kb);
        fh8 b  = *(const fh8*)(ws + (o0 + r16) * XS + kb);
        acc0 = __builtin_amdgcn_mfma_f32_16x16x32_f16(a0, b, acc0, 0, 0, 0);
        acc1 = __builtin_amdgcn_mfma_f32_16x16x32_f16(a1, b, acc1, 0, 0, 0);
    }
    #pragma unroll
    for (int r = 0; r < 4; r++) {
        float v0 = acc0[r] > 0.f ? acc0[r] : 0.f;
        float v1 = acc1[r] > 0.f ? acc1[r] : 0.f;
        hb[(n0 + q * 4 + r) * HH + o0 + r16]      = f2h(v0);
        hb[(n0 + 16 + q * 4 + r) * HH + o0 + r16] = f2h(v1);
    }
}

// ---------------------------------------------------------------------------
// Geo kernel v18: split-K x2, NB=80, 40 bins/block -- the R5 pre-committed
// fallback. R6 post-mortem: v17 (1 block/CU full-depth) hit the falsifier
// (101us): barriers with no co-resident block = +39us, swamping the fused
// norm's savings. 2 blocks/CU cross-overlap is worth ~40us and is the
// load-bearing property. v18 keeps v14's proven shell {500 blocks single
// round, 2/CU, 8 o-waves, identical W2/gather/store patterns} and banks
// half of v17's traffic win: ONE fp16 partial slice instead of three
// (geo -10.2 MB write, norm -10.2 MB read), and all 40 bins of conn fit
// LDS at once (52.5 KB, CPS=41 bank pad) -- chunk machinery deleted.
// pch 23 KB + cp 52.5 KB = 75.5 KB -> 2 blocks/CU.
// Deterministic partials: ks=0 -> fp32 d_out, ks=1 -> fp16 parts.
// ---------------------------------------------------------------------------
__global__ __launch_bounds__(512, 2) void geo_kernel(
    const int*   __restrict__ conn_idx, const float* __restrict__ conn_w,
    const unsigned short* __restrict__ W2, const unsigned short* __restrict__ hb,
    float* __restrict__ out, unsigned short* __restrict__ parts) {
    __shared__ __align__(16) unsigned short pch[2 * CB];        // 23040 B
    __shared__ __align__(16) unsigned short cp[NB * CPS * 8];   // 52480 B

    const int tid  = threadIdx.x;
    const int ks   = blockIdx.x & 1;             // K-slice 0..1
    const int n0   = (blockIdx.x >> 1) * NB;     // 0..249 * 80
    const int wv   = tid >> 6;                   // wave 0..7 = o-frag
    const int lane = tid & 63;
    const int q    = lane >> 4;
    const int r16  = lane & 15;
    const int j8   = tid & 7;                    // 16B segment of h row
    const int v0   = tid >> 3;                   // vertex 0..63 (lo also +64)
    const bool lo  = (v0 < 16);                  // rows 64..79
    const int bbase = ks * NBIN;
    const int Sbase = ks * (NBIN * 2);           // first 32-k step

    // All 40 bins of conn -> LDS, packed cp[v][cc] = [i0,i1,i2,w0,w1,w2,0,0]
    for (int e = tid; e < NB * NBIN; e += 512) {
        const int v = e / NBIN, cc = e - v * NBIN;
        const int g = (n0 + v) * (PT * KK) + (bbase + cc) * KK;
        u16x8 pk;
        pk[0] = (unsigned short)conn_idx[g];
        pk[1] = (unsigned short)conn_idx[g + 1];
        pk[2] = (unsigned short)conn_idx[g + 2];
        pk[3] = f2h(conn_w[g]);
        pk[4] = f2h(conn_w[g + 1]);
        pk[5] = f2h(conn_w[g + 2]);
        pk[6] = 0; pk[7] = 0;
        *(u16x8*)(cp + (v * CPS + cc) * 8) = pk;
    }

    f32x4 acc[5];
    #pragma unroll
    for (int m = 0; m < 5; m++) acc[m] = (f32x4){0.f, 0.f, 0.f, 0.f};

    u16x8 pa, pc;        // packed conn for rows v0 and (lo) v0+64
    fh8   hva0, hva1, hva2, hvc0, hvc1, hvc2;

    auto loadg = [&](int cc) {                   // conn b128 + 3..6 gathers
        pa = *(const u16x8*)(cp + (v0 * CPS + cc) * 8);
        hva0 = *(const fh8*)(hb + (int)pa[0] * HH + j8 * 8);
        hva1 = *(const fh8*)(hb + (int)pa[1] * HH + j8 * 8);
        hva2 = *(const fh8*)(hb + (int)pa[2] * HH + j8 * 8);
        if (lo) {                                // wave-uniform (waves 0..1)
            pc = *(const u16x8*)(cp + ((v0 + 64) * CPS + cc) * 8);
            hvc0 = *(const fh8*)(hb + (int)pc[0] * HH + j8 * 8);
            hvc1 = *(const fh8*)(hb + (int)pc[1] * HH + j8 * 8);
            hvc2 = *(const fh8*)(hb + (int)pc[2] * HH + j8 * 8);
        }
    };
    auto cwr = [&](unsigned short* buf) {        // combine + 1..2 LDS b128 writes
        const _Float16 a0 = u2h(pa[3]), a1 = u2h(pa[4]), a2 = u2h(pa[5]);
        const fh8 A0 = {a0, a0, a0, a0, a0, a0, a0, a0};
        const fh8 A1 = {a1, a1, a1, a1, a1, a1, a1, a1};
        const fh8 A2 = {a2, a2, a2, a2, a2, a2, a2, a2};
        fh8 ra = hva0 * A0 + hva1 * A1 + hva2 * A2;
        *(fh8*)(buf + v0 * RS + j8 * 8) = ra;
        if (lo) {
            const _Float16 c0 = u2h(pc[3]), c1 = u2h(pc[4]), c2 = u2h(pc[5]);
            const fh8 C0 = {c0, c0, c0, c0, c0, c0, c0, c0};
            const fh8 C1 = {c1, c1, c1, c1, c1, c1, c1, c1};
            const fh8 C2 = {c2, c2, c2, c2, c2, c2, c2, c2};
            fh8 rc = hvc0 * C0 + hvc1 * C1 + hvc2 * C2;
            *(fh8*)(buf + (v0 + 64) * RS + j8 * 8) = rc;
        }
    };
    auto mfmaph = [&](const unsigned short* buf, int cc) {   // 10 MFMA/wave
        const unsigned short* wp =
            W2 + (Sbase + cc * 2) * 4096 + (wv * 16 + r16) * 32 + q * 8;
        const fh8 bf0 = *(const fh8*)(wp);
        const fh8 bf1 = *(const fh8*)(wp + 4096);
        #pragma unroll
        for (int s = 0; s < 2; s++) {
            const int ao = s * 32 + q * 8;
            const fh8 bf = s ? bf1 : bf0;
            #pragma unroll
            for (int m = 0; m < 5; m++) {
                fh8 af = *(const fh8*)(buf + (m * 16 + r16) * RS + ao);
                acc[m] = __builtin_amdgcn_mfma_f32_16x16x32_f16(af, bf, acc[m], 0, 0, 0);
            }
        }
    };

    __syncthreads();                             // cp visible

    // Prologue: bin 0 staged into buffer 0
    loadg(0);
    cwr(pch);
    __syncthreads();

    #pragma unroll 1
    for (int cc = 0; cc < NBIN; cc++) {
        if (cc + 1 < NBIN) loadg(cc + 1);        // gathers in flight over MFMA
        mfmaph(&pch[(cc & 1) * CB], cc);
        if (cc + 1 < NBIN) cwr(&pch[((cc + 1) & 1) * CB]);
        __syncthreads();
    }

    // Partial store. D layout: row = q*4+reg, col = r16. 250*80 = 20000
    // exactly -> no guards. One writer per element per stage.
    if (ks == 0) {
        #pragma unroll
        for (int m = 0; m < 5; m++) {
            const int rb = n0 + m * 16 + q * 4;
            #pragma unroll
            for (int r = 0; r < 4; r++)
                out[(rb + r) * OO + wv * 16 + r16] = acc[m][r];
        }
    } else {
        #pragma unroll
        for (int m = 0; m < 5; m++) {
            const int rb = n0 + m * 16 + q * 4;
            #pragma unroll
            for (int r = 0; r < 4; r++)
                parts[(rb + r) * OO + wv * 16 + r16] = f2h(acc[m][r]);
        }
    }
}

// ---------------------------------------------------------------------------
// Epilogue v18: v = out + part + bg; out = v*rsqrt(sum v^2). Vectorized:
// 32 rows/block, 8 threads/row; lane l owns cols [l*16, l*16+16).
// ---------------------------------------------------------------------------
__global__ __launch_bounds__(256) void norm_kernel(
    float* __restrict__ out, const unsigned short* __restrict__ parts,
    const float* __restrict__ bg) {
    const int tid  = threadIdx.x;
    const int n    = blockIdx.x * 32 + (tid >> 3);
    const int l    = tid & 7;
    const int base = n * OO + l * 16;            // 16-float col slice

    float4 o4[4];
    #pragma unroll
    for (int i = 0; i < 4; i++)
        o4[i] = *(const float4*)(out + base + i * 4);

    u16x8 p0 = *(const u16x8*)(parts + base);
    u16x8 p1 = *(const u16x8*)(parts + base + 8);

    float4 b4[4];
    #pragma unroll
    for (int i = 0; i < 4; i++)
        b4[i] = *(const float4*)(bg + l * 16 + i * 4);

    float v[16];
    float s = 0.f;
    #pragma unroll
    for (int i = 0; i < 16; i++) {
        const float ov = (i & 3) == 0 ? o4[i >> 2].x :
                         (i & 3) == 1 ? o4[i >> 2].y :
                         (i & 3) == 2 ? o4[i >> 2].z : o4[i >> 2].w;
        const float bv = (i & 3) == 0 ? b4[i >> 2].x :
                         (i & 3) == 1 ? b4[i >> 2].y :
                         (i & 3) == 2 ? b4[i >> 2].z : b4[i >> 2].w;
        const float pv = h2f((i < 8) ? p0[i] : p1[i & 7]);
        v[i] = ov + pv + bv;
        s += v[i] * v[i];
    }
    for (int off = 4; off; off >>= 1) s += __shfl_down(s, off, 8);
    const float r = rsqrtf(__shfl(s, 0, 8));
    #pragma unroll
    for (int i = 0; i < 4; i++) {
        float4 w = {v[i * 4] * r, v[i * 4 + 1] * r,
                    v[i * 4 + 2] * r, v[i * 4 + 3] * r};
        *(float4*)(out + base + i * 4) = w;
    }
}

// ---------------------------------------------------------------------------
extern "C" void kernel_launch(void* const* d_in, const int* in_sizes, int n_in,
                              void* d_out, int out_size, void* d_ws, size_t ws_size,
                              hipStream_t stream) {
    const float* x        = (const float*)d_in[0];
    const int*   conn_idx = (const int*)  d_in[1];
    const float* conn_w   = (const float*)d_in[2];
    const float* W1       = (const float*)d_in[3];
    const float* Wg       = (const float*)d_in[4];
    const float* bg       = (const float*)d_in[5];
    float*       out      = (float*)d_out;

    unsigned short* W2    = (unsigned short*)d_ws;         // 655,360 fp16 (1.31 MB)
    unsigned short* hb    = W2 + OO * KTOT;                // 1,280,000 fp16 (2.56 MB)
    unsigned short* parts = hb + NV * HH;                  // 2,560,000 fp16 (5.12 MB)

    hipLaunchKernelGGL(prep_kernel, dim3(128 + NV / 32), dim3(256), 0, stream,
                       Wg, x, W1, W2, hb);
    hipLaunchKernelGGL(geo_kernel, dim3(2 * (NV / NB)), dim3(512), 0, stream,
                       conn_idx, conn_w, W2, hb, out, parts);
    hipLaunchKernelGGL(norm_kernel, dim3(NV / 32), dim3(256), 0, stream,
                       out, parts, bg);
}